// Round 1
// baseline (3929.226 us; speedup 1.0000x reference)
//
#include <hip/hip_runtime.h>
#include <math.h>

#define kD 2048
#define kH 32
#define kN 64
#define kS 2048

// ---------------- LayerNorm (ln1) ----------------
__global__ __launch_bounds__(256) void ln1_kernel(
    const float* __restrict__ x, const float* __restrict__ w, const float* __restrict__ b,
    float* __restrict__ xn, float* __restrict__ state1_out)
{
  int t = blockIdx.x;
  const float* row = x + (size_t)t * kD;
  float s = 0.f, s2 = 0.f;
  for (int d = threadIdx.x; d < kD; d += 256) {
    float v = row[d]; s += v; s2 += v * v;
  }
  #pragma unroll
  for (int o = 32; o > 0; o >>= 1) { s += __shfl_down(s, o); s2 += __shfl_down(s2, o); }
  __shared__ float ls[4], ls2[4];
  int wid = threadIdx.x >> 6;
  if ((threadIdx.x & 63) == 0) { ls[wid] = s; ls2[wid] = s2; }
  __syncthreads();
  s = ls[0] + ls[1] + ls[2] + ls[3];
  s2 = ls2[0] + ls2[1] + ls2[2] + ls2[3];
  float mean = s * (1.f / kD);
  float var = s2 * (1.f / kD) - mean * mean;
  float rstd = rsqrtf(var + 1e-5f);
  float* orow = xn + (size_t)t * kD;
  for (int d = threadIdx.x; d < kD; d += 256) {
    float v = (row[d] - mean) * rstd * w[d] + b[d];
    orow[d] = v;
    if (t == kS - 1) state1_out[d] = v;
  }
}

// ---------------- fp32 NT GEMM: C[t,j] = sum_d Amix[t,d] * W[j,d] (+resid) ----
// Amix[t,d] = A[t,d] + (prev[t,d]-A[t,d])*mixc[d], prev[0]=prev0 (if mixc!=null)
__global__ __launch_bounds__(256) void gemm_nt(
    const float* __restrict__ A, const float* __restrict__ prev0,
    const float* __restrict__ mixc, const float* __restrict__ W,
    float* __restrict__ C, const float* __restrict__ resid)
{
  __shared__ float As[16][132];
  __shared__ float Bs[16][132];
  int tid = threadIdx.x;
  int row0 = blockIdx.y * 128;
  int col0 = blockIdx.x * 128;
  int lc = tid & 15;           // k within tile
  int lr0 = (tid >> 4) * 8;    // 8 rows per thread for staging
  int tx = tid & 15;
  int ty = tid >> 4;
  float acc[8][8];
  #pragma unroll
  for (int m = 0; m < 8; m++)
    #pragma unroll
    for (int n = 0; n < 8; n++) acc[m][n] = 0.f;

  for (int k0 = 0; k0 < kD; k0 += 16) {
    #pragma unroll
    for (int rr = 0; rr < 8; rr++) {
      int r = lr0 + rr;
      int d = k0 + lc;
      int t = row0 + r;
      float cur = A[(size_t)t * kD + d];
      float val = cur;
      if (mixc) {
        float pv = (t > 0) ? A[(size_t)(t - 1) * kD + d] : prev0[d];
        val = cur + (pv - cur) * mixc[d];
      }
      As[lc][r] = val;
      Bs[lc][r] = W[(size_t)(col0 + r) * kD + d];
    }
    __syncthreads();
    #pragma unroll
    for (int kk = 0; kk < 16; kk++) {
      float a[8], bv[8];
      #pragma unroll
      for (int m = 0; m < 4; m++) { a[m] = As[kk][ty * 4 + m]; a[m + 4] = As[kk][64 + ty * 4 + m]; }
      #pragma unroll
      for (int n = 0; n < 4; n++) { bv[n] = Bs[kk][tx * 4 + n]; bv[n + 4] = Bs[kk][64 + tx * 4 + n]; }
      #pragma unroll
      for (int m = 0; m < 8; m++)
        #pragma unroll
        for (int n = 0; n < 8; n++) acc[m][n] = fmaf(a[m], bv[n], acc[m][n]);
    }
    __syncthreads();
  }
  #pragma unroll
  for (int m = 0; m < 8; m++) {
    int t = row0 + ((m < 4) ? (ty * 4 + m) : (64 + ty * 4 + (m - 4)));
    #pragma unroll
    for (int half = 0; half < 2; half++) {
      int j = col0 + half * 64 + tx * 4;
      float4 v;
      v.x = acc[m][half * 4 + 0]; v.y = acc[m][half * 4 + 1];
      v.z = acc[m][half * 4 + 2]; v.w = acc[m][half * 4 + 3];
      if (resid) {
        const float4 r4 = *(const float4*)(resid + (size_t)t * kD + j);
        v.x += r4.x; v.y += r4.y; v.z += r4.z; v.w += r4.w;
      }
      *(float4*)(C + (size_t)t * kD + j) = v;
    }
  }
}

// ---------------- fused small MLP per token ----------------
// MODE 0: gate = sigmoid(h) @ W2              (hidden act sigmoid)
// MODE 1: a    = sigmoid(h @ W2 + bias)       (no hidden act)
// MODE 2: wdec = exp(-0.606531*sigmoid(tanh(h) @ W2 + bias))
// MODE 3: v    = v + (vfirst - v)*sigmoid(h @ W2 + bias)   (in place on out)
template<int L, int MODE>
__global__ __launch_bounds__(256) void mlp_kernel(
    const float* __restrict__ xn, const float* __restrict__ state1,
    const float* __restrict__ mixc, const float* __restrict__ W1,
    const float* __restrict__ W2, const float* __restrict__ bias,
    float* __restrict__ out, const float* __restrict__ vfirst)
{
  __shared__ float xm[kD];
  __shared__ float hsh[L];
  __shared__ float hp[256];
  int t = blockIdx.x;
  int tid = threadIdx.x;
  const float* cur = xn + (size_t)t * kD;
  const float* prv = (t > 0) ? (xn + (size_t)(t - 1) * kD) : state1;
  for (int d = tid; d < kD; d += 256) {
    float c = cur[d];
    xm[d] = c + (prv[d] - c) * mixc[d];
  }
  __syncthreads();
  constexpr int G = 256 / L;
  int l = tid % L;
  int sub = tid / L;
  float acc = 0.f;
  #pragma unroll 4
  for (int d = sub; d < kD; d += G) acc += xm[d] * W1[(size_t)d * L + l];
  hp[tid] = acc;
  __syncthreads();
  if (tid < L) {
    float s = 0.f;
    #pragma unroll
    for (int g = 0; g < G; g++) s += hp[g * L + tid];
    if (MODE == 0) s = 1.f / (1.f + __expf(-s));
    else if (MODE == 2) s = tanhf(s);
    hsh[tid] = s;
  }
  __syncthreads();
  for (int d0 = tid; d0 < kD; d0 += 256) {
    float s = 0.f;
    #pragma unroll 16
    for (int l2 = 0; l2 < L; l2++) s = fmaf(hsh[l2], W2[(size_t)l2 * kD + d0], s);
    size_t off = (size_t)t * kD + d0;
    if (MODE == 0) {
      out[off] = s;
    } else if (MODE == 1) {
      out[off] = 1.f / (1.f + __expf(-(s + bias[d0])));
    } else if (MODE == 2) {
      float sg = 1.f / (1.f + __expf(-(s + bias[d0])));
      out[off] = __expf(-0.606531f * sg);
    } else {
      float sg = 1.f / (1.f + __expf(-(s + bias[d0])));
      float vv = out[off];
      out[off] = vv + (vfirst[off] - vv) * sg;
    }
  }
}

// ---------------- post: kk (normalized), k update, b ----------------
__global__ __launch_bounds__(256) void post_kernel(
    float* __restrict__ kArr, float* __restrict__ kkArr, float* __restrict__ bArr,
    const float* __restrict__ aArr, const float* __restrict__ k_k, const float* __restrict__ k_a)
{
  int gid = blockIdx.x * 4 + (threadIdx.x >> 6);   // t*H + h
  int lane = threadIdx.x & 63;
  int h = gid & (kH - 1);
  size_t off = (size_t)gid * kN + lane;
  float kv = kArr[off];
  float kkv = kv * k_k[h * kN + lane];
  float ss = kkv * kkv;
  #pragma unroll
  for (int o = 32; o > 0; o >>= 1) ss += __shfl_xor(ss, o);
  float scale = 1.f / fmaxf(sqrtf(ss), 1e-12f);
  float kkf = kkv * scale;
  kkArr[off] = kkf;
  float av = aArr[off];
  bArr[off] = kkf * av;
  kArr[off] = kv * (1.f + (av - 1.f) * k_a[h * kN + lane]);
}

// ---------------- sequential scan ----------------
// grid: kH * 8 blocks of 64 threads. Block b: head h=b>>3, rows (b&7)*8 .. +7.
// Wave layout: lane = localRow*8 + q; lane owns s[i][q*8 .. q*8+7] in regs.
// All reductions intra-octet via shfl_xor; no LDS, no barriers.
__global__ __launch_bounds__(64) void scan_kernel(
    const float* __restrict__ s0_in, const float* __restrict__ rA, const float* __restrict__ wA,
    const float* __restrict__ kA, const float* __restrict__ vA, const float* __restrict__ kkA,
    const float* __restrict__ bA, float* __restrict__ y, float* __restrict__ s_out)
{
  int blk = blockIdx.x;
  int h = blk >> 3;
  int il = threadIdx.x >> 3;
  int i = ((blk & 7) << 3) + il;
  int q = threadIdx.x & 7;
  int j0 = q << 3;
  size_t srow = ((size_t)(h * kN + i)) * kN + j0;
  float4 sA = *(const float4*)(s0_in + srow);
  float4 sB = *(const float4*)(s0_in + srow + 4);
  size_t voff = (size_t)h * kN + j0;
  const float* pr = rA + voff;
  const float* pw = wA + voff;
  const float* pk = kA + voff;
  const float* pa = kkA + voff;
  const float* pb = bA + voff;
  const float* pv = vA + (size_t)h * kN + i;
  float* py = y + (size_t)h * kN + i;

  float4 nr0 = *(const float4*)pr, nr1 = *(const float4*)(pr + 4);
  float4 nw0 = *(const float4*)pw, nw1 = *(const float4*)(pw + 4);
  float4 nk0 = *(const float4*)pk, nk1 = *(const float4*)(pk + 4);
  float4 na0 = *(const float4*)pa, na1 = *(const float4*)(pa + 4);
  float4 nb0 = *(const float4*)pb, nb1 = *(const float4*)(pb + 4);
  float nvi = *pv;

  for (int t = 0; t < kS; t++) {
    float4 r0 = nr0, r1 = nr1, w0 = nw0, w1 = nw1, k0 = nk0, k1 = nk1;
    float4 a0 = na0, a1 = na1, b0 = nb0, b1 = nb1;
    float vi = nvi;
    pr += kD; pw += kD; pk += kD; pa += kD; pb += kD; pv += kD;
    if (t < kS - 1) {   // prefetch next step
      nr0 = *(const float4*)pr; nr1 = *(const float4*)(pr + 4);
      nw0 = *(const float4*)pw; nw1 = *(const float4*)(pw + 4);
      nk0 = *(const float4*)pk; nk1 = *(const float4*)(pk + 4);
      na0 = *(const float4*)pa; na1 = *(const float4*)(pa + 4);
      nb0 = *(const float4*)pb; nb1 = *(const float4*)(pb + 4);
      nvi = *pv;
    }
    // sa_i = sum_j s[i][j] * (-kk[j])
    float sa = sA.x * a0.x + sA.y * a0.y + sA.z * a0.z + sA.w * a0.w
             + sB.x * a1.x + sB.y * a1.y + sB.z * a1.z + sB.w * a1.w;
    sa += __shfl_xor(sa, 1); sa += __shfl_xor(sa, 2); sa += __shfl_xor(sa, 4);
    sa = -sa;
    // s = s*w + sa*b + vi*k
    sA.x = fmaf(sA.x, w0.x, fmaf(sa, b0.x, vi * k0.x));
    sA.y = fmaf(sA.y, w0.y, fmaf(sa, b0.y, vi * k0.y));
    sA.z = fmaf(sA.z, w0.z, fmaf(sa, b0.z, vi * k0.z));
    sA.w = fmaf(sA.w, w0.w, fmaf(sa, b0.w, vi * k0.w));
    sB.x = fmaf(sB.x, w1.x, fmaf(sa, b1.x, vi * k1.x));
    sB.y = fmaf(sB.y, w1.y, fmaf(sa, b1.y, vi * k1.y));
    sB.z = fmaf(sB.z, w1.z, fmaf(sa, b1.z, vi * k1.z));
    sB.w = fmaf(sB.w, w1.w, fmaf(sa, b1.w, vi * k1.w));
    // y_i = sum_j s_new[i][j]*r[j]
    float yv = sA.x * r0.x + sA.y * r0.y + sA.z * r0.z + sA.w * r0.w
             + sB.x * r1.x + sB.y * r1.y + sB.z * r1.z + sB.w * r1.w;
    yv += __shfl_xor(yv, 1); yv += __shfl_xor(yv, 2); yv += __shfl_xor(yv, 4);
    if (q == 0) *py = yv;
    py += kD;
  }
  *(float4*)(s_out + srow) = sA;
  *(float4*)(s_out + srow + 4) = sB;
}

// ---------------- output: groupnorm(y) * lnx + rkv, * gate (in place on y) ----
__global__ __launch_bounds__(256) void out_kernel(
    float* __restrict__ y, const float* __restrict__ rA, const float* __restrict__ kA,
    const float* __restrict__ vA, const float* __restrict__ r_k,
    const float* __restrict__ lnw, const float* __restrict__ lnb,
    const float* __restrict__ gate)
{
  int gid = blockIdx.x * 4 + (threadIdx.x >> 6);  // t*H + h
  int lane = threadIdx.x & 63;
  int h = gid & (kH - 1);
  size_t off = (size_t)gid * kN + lane;
  float yv = y[off];
  float s = yv, s2 = yv * yv;
  #pragma unroll
  for (int o = 32; o > 0; o >>= 1) { s += __shfl_xor(s, o); s2 += __shfl_xor(s2, o); }
  float mean = s * (1.f / kN);
  float var = s2 * (1.f / kN) - mean * mean;
  float o1 = (yv - mean) * rsqrtf(var + 0.00064f);
  int d = h * kN + lane;
  float ov = o1 * lnw[d] + lnb[d];
  float p = rA[off] * kA[off] * r_k[d];
  #pragma unroll
  for (int o = 32; o > 0; o >>= 1) p += __shfl_xor(p, o);
  float rkv = p * vA[off];
  y[off] = (ov + rkv) * gate[off];
}

extern "C" void kernel_launch(void* const* d_in, const int* in_sizes, int n_in,
                              void* d_out, int out_size, void* d_ws, size_t ws_size,
                              hipStream_t stream)
{
  const float* x      = (const float*)d_in[0];
  const float* state1 = (const float*)d_in[1];
  const float* state2 = (const float*)d_in[2];
  const float* vfirst = (const float*)d_in[3];
  const float* ln1w   = (const float*)d_in[4];
  const float* ln1b   = (const float*)d_in[5];
  const float* xr_c   = (const float*)d_in[6];
  const float* xw_c   = (const float*)d_in[7];
  const float* xk_c   = (const float*)d_in[8];
  const float* xv_c   = (const float*)d_in[9];
  const float* xa_c   = (const float*)d_in[10];
  const float* xg_c   = (const float*)d_in[11];
  const float* Wr     = (const float*)d_in[12];
  const float* Wk     = (const float*)d_in[13];
  const float* Wv     = (const float*)d_in[14];
  const float* Wo     = (const float*)d_in[15];
  const float* w1     = (const float*)d_in[16];
  const float* w2     = (const float*)d_in[17];
  const float* w0     = (const float*)d_in[18];
  const float* a1     = (const float*)d_in[19];
  const float* a2     = (const float*)d_in[20];
  const float* a0     = (const float*)d_in[21];
  const float* g1     = (const float*)d_in[22];
  const float* g2     = (const float*)d_in[23];
  const float* v1     = (const float*)d_in[24];
  const float* v2     = (const float*)d_in[25];
  const float* v0     = (const float*)d_in[26];
  const float* k_k    = (const float*)d_in[27];
  const float* k_a    = (const float*)d_in[28];
  const float* r_k    = (const float*)d_in[29];
  const float* lnxw   = (const float*)d_in[30];
  const float* lnxb   = (const float*)d_in[31];

  float* out0  = (float*)d_out;
  float* s1out = out0 + (size_t)kS * kD;
  float* s2out = s1out + kD;

  size_t SD = (size_t)kS * kD;
  float* ws  = (float*)d_ws;
  float* xnB = ws;
  float* rB  = ws + SD;
  float* kB  = ws + 2 * SD;
  float* vB  = ws + 3 * SD;
  float* wB  = ws + 4 * SD;
  float* aB  = ws + 5 * SD;
  float* kkB = ws + 6 * SD;
  float* bB  = ws + 7 * SD;
  float* gB  = ws + 8 * SD;
  float* yB  = ws + 9 * SD;

  ln1_kernel<<<kS, 256, 0, stream>>>(x, ln1w, ln1b, xnB, s1out);

  dim3 gg(16, 16);
  gemm_nt<<<gg, 256, 0, stream>>>(xnB, state1, xr_c, Wr, rB, nullptr);
  gemm_nt<<<gg, 256, 0, stream>>>(xnB, state1, xk_c, Wk, kB, nullptr);
  gemm_nt<<<gg, 256, 0, stream>>>(xnB, state1, xv_c, Wv, vB, nullptr);

  mlp_kernel<128, 0><<<kS, 256, 0, stream>>>(xnB, state1, xg_c, g1, g2, nullptr, gB, nullptr);
  mlp_kernel<64, 1><<<kS, 256, 0, stream>>>(xnB, state1, xa_c, a1, a2, a0, aB, nullptr);
  mlp_kernel<64, 2><<<kS, 256, 0, stream>>>(xnB, state1, xw_c, w1, w2, w0, wB, nullptr);
  mlp_kernel<32, 3><<<kS, 256, 0, stream>>>(xnB, state1, xv_c, v1, v2, v0, vB, vfirst);

  post_kernel<<<kS * kH / 4, 256, 0, stream>>>(kB, kkB, bB, aB, k_k, k_a);

  scan_kernel<<<kH * 8, 64, 0, stream>>>(state2, rB, wB, kB, vB, kkB, bB, yB, s2out);

  out_kernel<<<kS * kH / 4, 256, 0, stream>>>(yB, rB, kB, vB, r_k, lnxw, lnxb, gB);

  gemm_nt<<<gg, 256, 0, stream>>>(yB, nullptr, nullptr, Wo, out0, x);
}

// Round 2
// 1581.617 us; speedup vs baseline: 2.4843x; 2.4843x over previous
//
#include <hip/hip_runtime.h>
#include <math.h>

#define kD 2048
#define kH 32
#define kN 64
#define kS 2048

typedef unsigned short ushort_t;
typedef unsigned int uint32;

__device__ __forceinline__ ushort_t f2bf(float f) {
  uint32 u = __float_as_uint(f);
  u += 0x7fffu + ((u >> 16) & 1u);   // RNE
  return (ushort_t)(u >> 16);
}

// ---------------- LayerNorm (ln1) ----------------
__global__ __launch_bounds__(256) void ln1_kernel(
    const float* __restrict__ x, const float* __restrict__ w, const float* __restrict__ b,
    float* __restrict__ xn, float* __restrict__ state1_out)
{
  int t = blockIdx.x;
  const float* row = x + (size_t)t * kD;
  float s = 0.f, s2 = 0.f;
  for (int d = threadIdx.x; d < kD; d += 256) {
    float v = row[d]; s += v; s2 += v * v;
  }
  #pragma unroll
  for (int o = 32; o > 0; o >>= 1) { s += __shfl_down(s, o); s2 += __shfl_down(s2, o); }
  __shared__ float ls[4], ls2[4];
  int wid = threadIdx.x >> 6;
  if ((threadIdx.x & 63) == 0) { ls[wid] = s; ls2[wid] = s2; }
  __syncthreads();
  s = ls[0] + ls[1] + ls[2] + ls[3];
  s2 = ls2[0] + ls2[1] + ls2[2] + ls2[3];
  float mean = s * (1.f / kD);
  float var = s2 * (1.f / kD) - mean * mean;
  float rstd = rsqrtf(var + 1e-5f);
  float* orow = xn + (size_t)t * kD;
  for (int d = threadIdx.x; d < kD; d += 256) {
    float v = (row[d] - mean) * rstd * w[d] + b[d];
    orow[d] = v;
    if (t == kS - 1) state1_out[d] = v;
  }
}

// ---------------- mix + bf16 convert for r/k/v GEMM A operands ----------------
__global__ __launch_bounds__(256) void mix3_cvt(
    const float* __restrict__ xn, const float* __restrict__ s1,
    const float* __restrict__ cr, const float* __restrict__ ck, const float* __restrict__ cv,
    ushort_t* __restrict__ Ar, ushort_t* __restrict__ Ak, ushort_t* __restrict__ Av)
{
  int t = blockIdx.x;
  const float* cur = xn + (size_t)t * kD;
  const float* prv = (t > 0) ? (cur - kD) : s1;
  size_t base = (size_t)t * kD;
  for (int d = threadIdx.x; d < kD; d += 256) {
    float c = cur[d];
    float dx = prv[d] - c;
    Ar[base + d] = f2bf(c + dx * cr[d]);
    Ak[base + d] = f2bf(c + dx * ck[d]);
    Av[base + d] = f2bf(c + dx * cv[d]);
  }
}

// ---------------- fp32 -> bf16 elementwise (weights / y) ----------------
__global__ __launch_bounds__(256) void cvt_bf16(
    const float* __restrict__ in, ushort_t* __restrict__ out)
{
  int idx = blockIdx.x * 256 + threadIdx.x;   // one float4 per thread
  float4 v = ((const float4*)in)[idx];
  ushort_t o[4] = { f2bf(v.x), f2bf(v.y), f2bf(v.z), f2bf(v.w) };
  ((uint2*)out)[idx] = *(const uint2*)o;
}

// ---------------- bf16 MFMA NT GEMM: C[t,j] = sum_d A[t,d]*W[j,d] (+resid) ----
// 128x128 tile, BK=64, 4 waves, m97-style global_load_lds staging, XOR swizzle.
typedef __bf16 bf16x8 __attribute__((ext_vector_type(8)));
typedef float f32x4 __attribute__((ext_vector_type(4)));

__global__ __launch_bounds__(256) void gemm_bf16_nt(
    const ushort_t* __restrict__ A, const ushort_t* __restrict__ B,
    float* __restrict__ C, const float* __restrict__ resid)
{
  __shared__ __align__(16) ushort_t As[128 * 64];
  __shared__ __align__(16) ushort_t Bs[128 * 64];
  int tid = threadIdx.x;
  int w = tid >> 6, lane = tid & 63;
  int row0 = blockIdx.y * 128, col0 = blockIdx.x * 128;
  int wrow = (w >> 1) * 64, wcol = (w & 1) * 64;
  int quad = lane >> 4, r16 = lane & 15;
  f32x4 acc[4][4] = {};

  int lrow = lane >> 3;          // 0..7 row within 8-row staging chunk
  int lsw  = (lane & 7) ^ lrow;  // XOR-swizzled global chunk this lane fetches

  for (int k0 = 0; k0 < kD; k0 += 64) {
    #pragma unroll
    for (int n = 0; n < 4; n++) {
      int rr = w * 32 + n * 8 + lrow;
      int cc = k0 + lsw * 8;
      const ushort_t* ga = A + (size_t)(row0 + rr) * kD + cc;
      const ushort_t* gb = B + (size_t)(col0 + rr) * kD + cc;
      __builtin_amdgcn_global_load_lds(
          (const __attribute__((address_space(1))) uint32*)ga,
          (__attribute__((address_space(3))) uint32*)&As[(w * 32 + n * 8) * 64], 16, 0, 0);
      __builtin_amdgcn_global_load_lds(
          (const __attribute__((address_space(1))) uint32*)gb,
          (__attribute__((address_space(3))) uint32*)&Bs[(w * 32 + n * 8) * 64], 16, 0, 0);
    }
    __syncthreads();
    #pragma unroll
    for (int kk = 0; kk < 64; kk += 32) {
      bf16x8 af[4], bfr[4];
      #pragma unroll
      for (int i = 0; i < 4; i++) {
        int row = wrow + i * 16 + r16;
        int chunk = ((kk >> 3) + quad) ^ (r16 & 7);
        af[i] = *(const bf16x8*)&As[row * 64 + chunk * 8];
      }
      #pragma unroll
      for (int j = 0; j < 4; j++) {
        int row = wcol + j * 16 + r16;
        int chunk = ((kk >> 3) + quad) ^ (r16 & 7);
        bfr[j] = *(const bf16x8*)&Bs[row * 64 + chunk * 8];
      }
      #pragma unroll
      for (int i = 0; i < 4; i++)
        #pragma unroll
        for (int j = 0; j < 4; j++)
          acc[i][j] = __builtin_amdgcn_mfma_f32_16x16x32_bf16(af[i], bfr[j], acc[i][j], 0, 0, 0);
    }
    __syncthreads();
  }
  // epilogue: C/D layout col=lane&15, row=(lane>>4)*4+reg
  #pragma unroll
  for (int i = 0; i < 4; i++) {
    #pragma unroll
    for (int j = 0; j < 4; j++) {
      int col = col0 + wcol + j * 16 + r16;
      #pragma unroll
      for (int reg = 0; reg < 4; reg++) {
        int row = row0 + wrow + i * 16 + quad * 4 + reg;
        float v = acc[i][j][reg];
        if (resid) v += resid[(size_t)row * kD + col];
        C[(size_t)row * kD + col] = v;
      }
    }
  }
}

// ---------------- fused small MLP per token ----------------
template<int L, int MODE>
__global__ __launch_bounds__(256) void mlp_kernel(
    const float* __restrict__ xn, const float* __restrict__ state1,
    const float* __restrict__ mixc, const float* __restrict__ W1,
    const float* __restrict__ W2, const float* __restrict__ bias,
    float* __restrict__ out, const float* __restrict__ vfirst)
{
  __shared__ float xm[kD];
  __shared__ float hsh[L];
  __shared__ float hp[256];
  int t = blockIdx.x;
  int tid = threadIdx.x;
  const float* cur = xn + (size_t)t * kD;
  const float* prv = (t > 0) ? (xn + (size_t)(t - 1) * kD) : state1;
  for (int d = tid; d < kD; d += 256) {
    float c = cur[d];
    xm[d] = c + (prv[d] - c) * mixc[d];
  }
  __syncthreads();
  constexpr int G = 256 / L;
  int l = tid % L;
  int sub = tid / L;
  float acc = 0.f;
  #pragma unroll 4
  for (int d = sub; d < kD; d += G) acc += xm[d] * W1[(size_t)d * L + l];
  hp[tid] = acc;
  __syncthreads();
  if (tid < L) {
    float s = 0.f;
    #pragma unroll
    for (int g = 0; g < G; g++) s += hp[g * L + tid];
    if (MODE == 0) s = 1.f / (1.f + __expf(-s));
    else if (MODE == 2) s = tanhf(s);
    hsh[tid] = s;
  }
  __syncthreads();
  for (int d0 = tid; d0 < kD; d0 += 256) {
    float s = 0.f;
    #pragma unroll 16
    for (int l2 = 0; l2 < L; l2++) s = fmaf(hsh[l2], W2[(size_t)l2 * kD + d0], s);
    size_t off = (size_t)t * kD + d0;
    if (MODE == 0) {
      out[off] = s;
    } else if (MODE == 1) {
      out[off] = 1.f / (1.f + __expf(-(s + bias[d0])));
    } else if (MODE == 2) {
      float sg = 1.f / (1.f + __expf(-(s + bias[d0])));
      out[off] = __expf(-0.606531f * sg);
    } else {
      float sg = 1.f / (1.f + __expf(-(s + bias[d0])));
      float vv = out[off];
      out[off] = vv + (vfirst[off] - vv) * sg;
    }
  }
}

// ---------------- post: kk (normalized), k update, b ----------------
__global__ __launch_bounds__(256) void post_kernel(
    float* __restrict__ kArr, float* __restrict__ kkArr, float* __restrict__ bArr,
    const float* __restrict__ aArr, const float* __restrict__ k_k, const float* __restrict__ k_a)
{
  int gid = blockIdx.x * 4 + (threadIdx.x >> 6);
  int lane = threadIdx.x & 63;
  int h = gid & (kH - 1);
  size_t off = (size_t)gid * kN + lane;
  float kv = kArr[off];
  float kkv = kv * k_k[h * kN + lane];
  float ss = kkv * kkv;
  #pragma unroll
  for (int o = 32; o > 0; o >>= 1) ss += __shfl_xor(ss, o);
  float scale = 1.f / fmaxf(sqrtf(ss), 1e-12f);
  float kkf = kkv * scale;
  kkArr[off] = kkf;
  float av = aArr[off];
  bArr[off] = kkf * av;
  kArr[off] = kv * (1.f + (av - 1.f) * k_a[h * kN + lane]);
}

// ---------------- sequential scan: 4-slot register ring, prefetch distance 3 --
#define DOT8(x0, x1, y0, y1) \
  ((x0).x*(y0).x + (x0).y*(y0).y + (x0).z*(y0).z + (x0).w*(y0).w + \
   (x1).x*(y1).x + (x1).y*(y1).y + (x1).z*(y1).z + (x1).w*(y1).w)

__global__ __launch_bounds__(64) void scan_kernel(
    const float* __restrict__ s0_in, const float* __restrict__ rA, const float* __restrict__ wA,
    const float* __restrict__ kA, const float* __restrict__ vA, const float* __restrict__ kkA,
    const float* __restrict__ bA, float* __restrict__ y, float* __restrict__ s_out)
{
  int blk = blockIdx.x;
  int h = blk >> 3;
  int il = threadIdx.x >> 3;
  int i = ((blk & 7) << 3) + il;
  int q = threadIdx.x & 7;
  int j0 = q << 3;
  size_t srow = ((size_t)(h * kN + i)) * kN + j0;
  float4 sA = *(const float4*)(s0_in + srow);
  float4 sB = *(const float4*)(s0_in + srow + 4);
  size_t voff = (size_t)h * kN + j0;
  const float* pr = rA + voff;
  const float* pw = wA + voff;
  const float* pk = kA + voff;
  const float* pa = kkA + voff;
  const float* pb = bA + voff;
  const float* pv = vA + (size_t)h * kN + i;
  float* py = y + (size_t)h * kN + i;

  float4 R0[4], R1[4], W0[4], W1[4], K0[4], K1[4], A0[4], A1[4], B0[4], B1[4];
  float V[4];
  #pragma unroll
  for (int s = 0; s < 3; s++) {
    R0[s] = *(const float4*)pr; R1[s] = *(const float4*)(pr + 4);
    W0[s] = *(const float4*)pw; W1[s] = *(const float4*)(pw + 4);
    K0[s] = *(const float4*)pk; K1[s] = *(const float4*)(pk + 4);
    A0[s] = *(const float4*)pa; A1[s] = *(const float4*)(pa + 4);
    B0[s] = *(const float4*)pb; B1[s] = *(const float4*)(pb + 4);
    V[s] = *pv;
    pr += kD; pw += kD; pk += kD; pa += kD; pb += kD; pv += kD;
  }

  for (int t = 0; t < kS; t += 4) {
    #pragma unroll
    for (int s = 0; s < 4; s++) {
      const int ps = (s + 3) & 3;
      // prefetch step t+s+3 into slot ps (its step t+s-1 data already consumed)
      R0[ps] = *(const float4*)pr; R1[ps] = *(const float4*)(pr + 4);
      W0[ps] = *(const float4*)pw; W1[ps] = *(const float4*)(pw + 4);
      K0[ps] = *(const float4*)pk; K1[ps] = *(const float4*)(pk + 4);
      A0[ps] = *(const float4*)pa; A1[ps] = *(const float4*)(pa + 4);
      B0[ps] = *(const float4*)pb; B1[ps] = *(const float4*)(pb + 4);
      V[ps] = *pv;
      pr += kD; pw += kD; pk += kD; pa += kD; pb += kD; pv += kD;
      // compute step t+s from slot s
      float sa = DOT8(sA, sB, A0[s], A1[s]);
      sa += __shfl_xor(sa, 1); sa += __shfl_xor(sa, 2); sa += __shfl_xor(sa, 4);
      sa = -sa;
      float vi = V[s];
      sA.x = fmaf(sA.x, W0[s].x, fmaf(sa, B0[s].x, vi * K0[s].x));
      sA.y = fmaf(sA.y, W0[s].y, fmaf(sa, B0[s].y, vi * K0[s].y));
      sA.z = fmaf(sA.z, W0[s].z, fmaf(sa, B0[s].z, vi * K0[s].z));
      sA.w = fmaf(sA.w, W0[s].w, fmaf(sa, B0[s].w, vi * K0[s].w));
      sB.x = fmaf(sB.x, W1[s].x, fmaf(sa, B1[s].x, vi * K1[s].x));
      sB.y = fmaf(sB.y, W1[s].y, fmaf(sa, B1[s].y, vi * K1[s].y));
      sB.z = fmaf(sB.z, W1[s].z, fmaf(sa, B1[s].z, vi * K1[s].z));
      sB.w = fmaf(sB.w, W1[s].w, fmaf(sa, B1[s].w, vi * K1[s].w));
      float yv = DOT8(sA, sB, R0[s], R1[s]);
      yv += __shfl_xor(yv, 1); yv += __shfl_xor(yv, 2); yv += __shfl_xor(yv, 4);
      if (q == 0) *py = yv;
      py += kD;
    }
  }
  *(float4*)(s_out + srow) = sA;
  *(float4*)(s_out + srow + 4) = sB;
}

// ---------------- output: groupnorm(y)*lnx + rkv, * gate (in place on y) ------
__global__ __launch_bounds__(256) void out_kernel(
    float* __restrict__ y, const float* __restrict__ rA, const float* __restrict__ kA,
    const float* __restrict__ vA, const float* __restrict__ r_k,
    const float* __restrict__ lnw, const float* __restrict__ lnb,
    const float* __restrict__ gate)
{
  int gid = blockIdx.x * 4 + (threadIdx.x >> 6);
  int lane = threadIdx.x & 63;
  int h = gid & (kH - 1);
  size_t off = (size_t)gid * kN + lane;
  float yv = y[off];
  float s = yv, s2 = yv * yv;
  #pragma unroll
  for (int o = 32; o > 0; o >>= 1) { s += __shfl_xor(s, o); s2 += __shfl_xor(s2, o); }
  float mean = s * (1.f / kN);
  float var = s2 * (1.f / kN) - mean * mean;
  float o1 = (yv - mean) * rsqrtf(var + 0.00064f);
  int d = h * kN + lane;
  float ov = o1 * lnw[d] + lnb[d];
  float p = rA[off] * kA[off] * r_k[d];
  #pragma unroll
  for (int o = 32; o > 0; o >>= 1) p += __shfl_xor(p, o);
  float rkv = p * vA[off];
  y[off] = (ov + rkv) * gate[off];
}

extern "C" void kernel_launch(void* const* d_in, const int* in_sizes, int n_in,
                              void* d_out, int out_size, void* d_ws, size_t ws_size,
                              hipStream_t stream)
{
  const float* x      = (const float*)d_in[0];
  const float* state1 = (const float*)d_in[1];
  const float* state2 = (const float*)d_in[2];
  const float* vfirst = (const float*)d_in[3];
  const float* ln1w   = (const float*)d_in[4];
  const float* ln1b   = (const float*)d_in[5];
  const float* xr_c   = (const float*)d_in[6];
  const float* xw_c   = (const float*)d_in[7];
  const float* xk_c   = (const float*)d_in[8];
  const float* xv_c   = (const float*)d_in[9];
  const float* xa_c   = (const float*)d_in[10];
  const float* xg_c   = (const float*)d_in[11];
  const float* Wr     = (const float*)d_in[12];
  const float* Wk     = (const float*)d_in[13];
  const float* Wv     = (const float*)d_in[14];
  const float* Wo     = (const float*)d_in[15];
  const float* w1     = (const float*)d_in[16];
  const float* w2     = (const float*)d_in[17];
  const float* w0     = (const float*)d_in[18];
  const float* a1     = (const float*)d_in[19];
  const float* a2     = (const float*)d_in[20];
  const float* a0     = (const float*)d_in[21];
  const float* g1     = (const float*)d_in[22];
  const float* g2     = (const float*)d_in[23];
  const float* v1     = (const float*)d_in[24];
  const float* v2     = (const float*)d_in[25];
  const float* v0     = (const float*)d_in[26];
  const float* k_k    = (const float*)d_in[27];
  const float* k_a    = (const float*)d_in[28];
  const float* r_k    = (const float*)d_in[29];
  const float* lnxw   = (const float*)d_in[30];
  const float* lnxb   = (const float*)d_in[31];

  float* out0  = (float*)d_out;
  float* s1out = out0 + (size_t)kS * kD;
  float* s2out = s1out + kD;

  size_t SD = (size_t)kS * kD;
  float* ws  = (float*)d_ws;
  float* xnB = ws;
  float* rB  = ws + SD;
  float* kB  = ws + 2 * SD;
  float* vB  = ws + 3 * SD;
  float* wB  = ws + 4 * SD;
  float* aB  = ws + 5 * SD;
  float* kkB = ws + 6 * SD;
  float* bB  = ws + 7 * SD;
  float* gB  = ws + 8 * SD;
  float* yB  = ws + 9 * SD;
  // bf16 overlays on dead fp32 regions (D==S so D*D and S*D are both SD elems)
  ushort_t* ArB = (ushort_t*)kkB;        // first half of kkB region
  ushort_t* AkB = (ushort_t*)kkB + SD;   // second half of kkB region
  ushort_t* AvB = (ushort_t*)bB;
  ushort_t* Wsh = (ushort_t*)yB;         // shared weight buf for r/k/v gemms
  ushort_t* WoB = (ushort_t*)rB;         // rB dead after out_kernel
  ushort_t* AyB = (ushort_t*)aB;         // aB dead after post_kernel

  ln1_kernel<<<kS, 256, 0, stream>>>(x, ln1w, ln1b, xnB, s1out);
  mix3_cvt<<<kS, 256, 0, stream>>>(xnB, state1, xr_c, xk_c, xv_c, ArB, AkB, AvB);

  dim3 gg(16, 16);
  const int CVT_BLKS = (int)(SD / 4 / 256);   // 4 floats per thread
  cvt_bf16<<<CVT_BLKS, 256, 0, stream>>>(Wr, Wsh);
  gemm_bf16_nt<<<gg, 256, 0, stream>>>(ArB, Wsh, rB, nullptr);
  cvt_bf16<<<CVT_BLKS, 256, 0, stream>>>(Wk, Wsh);
  gemm_bf16_nt<<<gg, 256, 0, stream>>>(AkB, Wsh, kB, nullptr);
  cvt_bf16<<<CVT_BLKS, 256, 0, stream>>>(Wv, Wsh);
  gemm_bf16_nt<<<gg, 256, 0, stream>>>(AvB, Wsh, vB, nullptr);

  mlp_kernel<128, 0><<<kS, 256, 0, stream>>>(xnB, state1, xg_c, g1, g2, nullptr, gB, nullptr);
  mlp_kernel<64, 1><<<kS, 256, 0, stream>>>(xnB, state1, xa_c, a1, a2, a0, aB, nullptr);
  mlp_kernel<64, 2><<<kS, 256, 0, stream>>>(xnB, state1, xw_c, w1, w2, w0, wB, nullptr);
  mlp_kernel<32, 3><<<kS, 256, 0, stream>>>(xnB, state1, xv_c, v1, v2, v0, vB, vfirst);

  post_kernel<<<kS * kH / 4, 256, 0, stream>>>(kB, kkB, bB, aB, k_k, k_a);

  scan_kernel<<<kH * 8, 64, 0, stream>>>(state2, rB, wB, kB, vB, kkB, bB, yB, s2out);

  out_kernel<<<kS * kH / 4, 256, 0, stream>>>(yB, rB, kB, vB, r_k, lnxw, lnxb, gB);

  cvt_bf16<<<CVT_BLKS, 256, 0, stream>>>(yB, AyB);
  cvt_bf16<<<CVT_BLKS, 256, 0, stream>>>(Wo, WoB);
  gemm_bf16_nt<<<gg, 256, 0, stream>>>(AyB, WoB, out0, x);
}